// Round 2
// baseline (339.672 us; speedup 1.0000x reference)
//
#include <hip/hip_runtime.h>
#include <cstdint>
#include <cstddef>

#define NH 16
#define ND 64
#define NK 256
#define NE 8
#define NV 196608
#define NBL 16384           // B*L = 4*4096
#define TOK 64              // tokens per block
#define ACC_STRIDE 257      // padded accum row stride (floats)

struct Primes { int p[NH]; };

// ---------------- K1: PQ assignment + EMA accumulation + normed_x ----------------
// Block: 256 threads, 64 tokens, one head. Thread tile: 4 tokens x 16 clusters.
// tid = tok_row*16 + cl_col ; tok_row 0..15 (4 tokens each), cl_col 0..15 (16 clusters each, c = i*16+cl_col)
__global__ __launch_bounds__(256, 2) void k_pq(
    const float* __restrict__ x, const float* __restrict__ means,
    const float* __restrict__ lnxs, const float* __restrict__ lnxb,
    float* __restrict__ out, uint8_t* __restrict__ cids,
    float* __restrict__ gsum, int* __restrict__ gcnt)
{
  // manual union: 16704 floats = 66816 B
  __shared__ __align__(16) float smem[16704];
  float4* sx4   = (float4*)smem;                 // [16 dc][64 tok]   (4096 f)
  float4* sm4   = (float4*)(smem + 4096);        // [8 dc][256 cl]    (8192 f, per half)
  float*  smsq  = smem + 12288;                  // [256]
  float*  lnsc  = smem + 12544;                  // [64]
  float*  lnbi  = smem + 12608;                  // [64]
  float*  accum = smem;                          // phase 2: [64 d][257]
  int*    scnt  = (int*)(smem + 16448);          // [256] (non-overlapping)

  const int tid     = threadIdx.x;
  const int h       = blockIdx.y;
  const int g0      = blockIdx.x * TOK;
  const int tok_row = tid >> 4;                  // 0..15
  const int cl_col  = tid & 15;                  // 0..15

  // ---- stage x tile: thread stages token t = tid>>2, float4s part*4..part*4+3 ----
  {
    const int t = tid >> 2, part = tid & 3;
    const float4* xs = (const float4*)(x + ((size_t)(g0 + t) * NH + h) * ND) + part * 4;
#pragma unroll
    for (int j = 0; j < 4; ++j) sx4[(part * 4 + j) * TOK + t] = xs[j];
  }
  if (tid < ND) { lnsc[tid] = lnxs[h * ND + tid]; lnbi[tid] = lnxb[h * ND + tid]; }
  scnt[tid] = 0;

  float acc[4][16];
#pragma unroll
  for (int j = 0; j < 4; ++j)
#pragma unroll
    for (int i = 0; i < 16; ++i) acc[j][i] = 0.f;

  // ---- main loop: two halves of d (32 each), means staged per half ----
  for (int half = 0; half < 2; ++half) {
    if (half) __syncthreads();                   // previous half's reads done
    {
      const float4* msrc = (const float4*)(means + ((size_t)h * NK + tid) * ND + half * 32);
      float mp = 0.f;
#pragma unroll
      for (int i = 0; i < 8; ++i) {
        float4 v = msrc[i];
        sm4[i * NK + tid] = v;
        mp += v.x * v.x + v.y * v.y + v.z * v.z + v.w * v.w;
      }
      if (half == 0) smsq[tid] = mp; else smsq[tid] += mp;
    }
    __syncthreads();

#pragma unroll 2
    for (int dc = 0; dc < 8; ++dc) {
      float4 xv[4];
#pragma unroll
      for (int j = 0; j < 4; ++j) xv[j] = sx4[(half * 8 + dc) * TOK + tok_row * 4 + j];
#pragma unroll
      for (int i = 0; i < 16; ++i) {
        float4 mv = sm4[dc * NK + i * 16 + cl_col];
#pragma unroll
        for (int j = 0; j < 4; ++j) {
          float a = acc[j][i];
          a = fmaf(xv[j].x, mv.x, a);
          a = fmaf(xv[j].y, mv.y, a);
          a = fmaf(xv[j].z, mv.z, a);
          a = fmaf(xv[j].w, mv.w, a);
          acc[j][i] = a;
        }
      }
    }
  }

  // ---- argmin: dist = msq - 2*dot (x_sq dropped: constant per token) ----
  int bk[4];
  {
    float bv[4]; int bi[4];
#pragma unroll
    for (int j = 0; j < 4; ++j) { bv[j] = 3.4e38f; bi[j] = 0; }
#pragma unroll
    for (int i = 0; i < 16; ++i) {
      const int c = i * 16 + cl_col;
      const float mq = smsq[c];
#pragma unroll
      for (int j = 0; j < 4; ++j) {
        float d = mq - 2.0f * acc[j][i];
        if (d < bv[j]) { bv[j] = d; bi[j] = c; }   // ascending c within thread
      }
    }
#pragma unroll
    for (int j = 0; j < 4; ++j) {
      float v = bv[j]; int c = bi[j];
#pragma unroll
      for (int m = 1; m < 16; m <<= 1) {
        float ov = __shfl_xor(v, m);
        int   oc = __shfl_xor(c, m);
        if (ov < v || (ov == v && oc < c)) { v = ov; c = oc; }
      }
      bk[j] = c;
    }
    if (cl_col == 0) {
#pragma unroll
      for (int j = 0; j < 4; ++j) {
        const int t = tok_row * 4 + j;
        cids[(size_t)(g0 + t) * NH + h] = (uint8_t)bk[j];
        atomicAdd(&scnt[bk[j]], 1);
      }
    }
  }

  // ---- normed_x -> out[0:56) ; thread handles token tid>>2, d-range (tid&3)*16.. ----
  {
    const int t = tid >> 2, q = tid & 3;
    float4 v[4];
    float s = 0.f, sq = 0.f;
#pragma unroll
    for (int j = 0; j < 4; ++j) {
      v[j] = sx4[(q * 4 + j) * TOK + t];
      s  += v[j].x + v[j].y + v[j].z + v[j].w;
      sq += v[j].x * v[j].x + v[j].y * v[j].y + v[j].z * v[j].z + v[j].w * v[j].w;
    }
    s  += __shfl_xor(s, 1);  sq += __shfl_xor(sq, 1);
    s  += __shfl_xor(s, 2);  sq += __shfl_xor(sq, 2);
    float mu  = s * (1.f / 64.f);
    float var = sq * (1.f / 64.f) - mu * mu;
    float rs  = rsqrtf(var + 1e-5f);
    float* orow = out + ((size_t)(g0 + t) * NH + h) * ND;
#pragma unroll
    for (int j = 0; j < 4; ++j) {
      const int dc = q * 4 + j;
      if (dc < 14) {                              // d < 56
        float4 o;
        o.x = (v[j].x - mu) * rs * lnsc[dc * 4 + 0] + lnbi[dc * 4 + 0];
        o.y = (v[j].y - mu) * rs * lnsc[dc * 4 + 1] + lnbi[dc * 4 + 1];
        o.z = (v[j].z - mu) * rs * lnsc[dc * 4 + 2] + lnbi[dc * 4 + 2];
        o.w = (v[j].w - mu) * rs * lnsc[dc * 4 + 3] + lnbi[dc * 4 + 3];
        ((float4*)orow)[dc] = o;
      }
    }
  }

  // ---- EMA: grab this thread's x slice (d-chunk = cl_col) before overwrite ----
  float4 xr[4];
#pragma unroll
  for (int j = 0; j < 4; ++j) xr[j] = sx4[cl_col * TOK + tok_row * 4 + j];

  __syncthreads();                               // all sx reads complete
  for (int idx = tid; idx < 64 * ACC_STRIDE; idx += 256) accum[idx] = 0.f;
  __syncthreads();

#pragma unroll
  for (int j = 0; j < 4; ++j) {
    const int b = bk[j];
    atomicAdd(&accum[(cl_col * 4 + 0) * ACC_STRIDE + b], xr[j].x);
    atomicAdd(&accum[(cl_col * 4 + 1) * ACC_STRIDE + b], xr[j].y);
    atomicAdd(&accum[(cl_col * 4 + 2) * ACC_STRIDE + b], xr[j].z);
    atomicAdd(&accum[(cl_col * 4 + 3) * ACC_STRIDE + b], xr[j].w);
  }
  __syncthreads();

  // ---- flush: thread tid owns cluster tid; skip empty ----
  const int cnt = scnt[tid];
  if (cnt > 0) atomicAdd(&gcnt[h * NK + tid], cnt);
  const bool act = cnt > 0;
#pragma unroll 4
  for (int d = 0; d < ND; ++d) {
    if (act) atomicAdd(&gsum[((size_t)h * ND + d) * NK + tid], accum[d * ACC_STRIDE + tid]);
  }
}

// ---------------- K2: bigram hash + embedding gather + LN_y -> out[56:64) ----------------
__global__ __launch_bounds__(256) void k_ngram(
    const uint8_t* __restrict__ cids, const float* __restrict__ embed,
    const float* __restrict__ lys, const float* __restrict__ lyb,
    float* __restrict__ out, Primes pr)
{
  const int i = blockIdx.x * 256 + threadIdx.x;  // 0 .. NBL*NH-1
  const int h = i & 15;
  const int g = i >> 4;
  const int l = g & 4095;                        // L = 4096

  int cid  = (int)cids[i];
  int prev = (l == 0) ? 0 : (int)cids[i - NH];
  int ng   = cid + (prev << 8);
  int hp1  = h + 1;
  int v    = ng * hp1 + hp1;
  const int p = pr.p[h];
  while (v >= p) v -= p;
  if (v >= NV) v -= NV;

  const float4* e4 = (const float4*)(embed + ((size_t)(v + NV * h)) * NE);
  float4 y0 = e4[0], y1 = e4[1];

  float s = ((y0.x + y0.y) + (y0.z + y0.w)) + ((y1.x + y1.y) + (y1.z + y1.w));
  float mu = s * 0.125f;
  float q = y0.x * y0.x + y0.y * y0.y + y0.z * y0.z + y0.w * y0.w
          + y1.x * y1.x + y1.y * y1.y + y1.z * y1.z + y1.w * y1.w;
  float var = q * 0.125f - mu * mu;
  float rs  = rsqrtf(var + 1e-5f);

  const float* sc = lys + h * NE;
  const float* bi = lyb + h * NE;
  float4 o0, o1;
  o0.x = (y0.x - mu) * rs * sc[0] + bi[0];
  o0.y = (y0.y - mu) * rs * sc[1] + bi[1];
  o0.z = (y0.z - mu) * rs * sc[2] + bi[2];
  o0.w = (y0.w - mu) * rs * sc[3] + bi[3];
  o1.x = (y1.x - mu) * rs * sc[4] + bi[4];
  o1.y = (y1.y - mu) * rs * sc[5] + bi[5];
  o1.z = (y1.z - mu) * rs * sc[6] + bi[6];
  o1.w = (y1.w - mu) * rs * sc[7] + bi[7];

  float4* orow = (float4*)(out + ((size_t)g * NH + h) * ND + 56);
  orow[0] = o0;
  orow[1] = o1;
}

// ---------------- K3: finalize new_means ----------------
__global__ __launch_bounds__(256) void k_means(
    const float* __restrict__ means, const float* __restrict__ gsum,
    const int* __restrict__ gcnt, float* __restrict__ newm)
{
  const int i = blockIdx.x * 256 + threadIdx.x;  // flat [h][k][d]
  const int d = i & 63;
  const int k = (i >> 6) & 255;
  const int h = i >> 14;
  float cnt = (float)gcnt[h * NK + k];
  float sx  = gsum[((size_t)h * ND + d) * NK + k];
  float mx  = sx / (1e-6f + cnt);
  newm[i] = 0.001f * mx + 0.999f * means[i];
}

extern "C" void kernel_launch(void* const* d_in, const int* in_sizes, int n_in,
                              void* d_out, int out_size, void* d_ws, size_t ws_size,
                              hipStream_t stream)
{
  const float* x     = (const float*)d_in[0];
  const float* means = (const float*)d_in[1];
  const float* embed = (const float*)d_in[2];
  const float* lnxs  = (const float*)d_in[3];
  const float* lnxb  = (const float*)d_in[4];
  const float* lys   = (const float*)d_in[5];
  const float* lyb   = (const float*)d_in[6];

  float* out  = (float*)d_out;
  float* newm = out + (size_t)NBL * NH * ND;

  float*   gsum = (float*)d_ws;
  int*     gcnt = (int*)((char*)d_ws + (size_t)NH * NK * ND * 4);
  uint8_t* cids = (uint8_t*)((char*)d_ws + (size_t)NH * NK * ND * 4 + (size_t)NH * NK * 4);

  hipMemsetAsync(d_ws, 0, (size_t)NH * NK * ND * 4 + (size_t)NH * NK * 4, stream);

  Primes pr;
  {
    int n = NV, c = 0;
    while (c < NH) {
      ++n;
      bool isp = true;
      for (int q = 2; (long long)q * q <= n; ++q)
        if (n % q == 0) { isp = false; break; }
      if (isp) pr.p[c++] = n;
    }
  }

  dim3 g1(NBL / TOK, NH);
  k_pq<<<g1, 256, 0, stream>>>(x, means, lnxs, lnxb, out, cids, gsum, gcnt);
  k_ngram<<<(NBL * NH) / 256, 256, 0, stream>>>(cids, embed, lys, lyb, out, pr);
  k_means<<<(NH * NK * ND) / 256, 256, 0, stream>>>(means, gsum, gcnt, newm);
}

// Round 3
// 336.746 us; speedup vs baseline: 1.0087x; 1.0087x over previous
//
#include <hip/hip_runtime.h>
#include <cstdint>
#include <cstddef>

#define NH 16
#define ND 64
#define NK 256
#define NE 8
#define NV 196608
#define NBL 16384           // B*L = 4*4096
#define TOK 64              // tokens per block
#define MROW 17             // means LDS row stride in float4 (68 floats = 272B, 16B-aligned)
#define ACC_STRIDE 257

struct Primes { int p[NH]; };

// ---------------- K1: PQ assignment + EMA accumulation + normed_x ----------------
// 512 threads: c = tid&31 (cluster col, T_cl=8 -> cl = i*32+c), r = tid>>5 (token row, T_tok=4)
__global__ __launch_bounds__(512, 4) void k_pq(
    const float* __restrict__ x, const float* __restrict__ means,
    const float* __restrict__ lnxs, const float* __restrict__ lnxb,
    float* __restrict__ out, uint8_t* __restrict__ cids,
    float* __restrict__ gsum, int* __restrict__ gcnt)
{
  // 17408 means(f) + 512 msq + 256 scnt = 18176 floats = 72704 B
  __shared__ __align__(16) float smem[18176];
  float4* sm4   = (float4*)smem;                 // [256 cl][17] (slot 0..15 used)
  float*  smsq2 = smem + 17408;                  // [2][256]
  int*    scnt  = (int*)(smem + 17920);          // [256]
  float*  accum = smem;                          // phase 2: [64 d][257] = 16448 f

  const int tid = threadIdx.x;
  const int c   = tid & 31;
  const int r   = tid >> 5;
  const int h   = blockIdx.y;
  const int g0  = blockIdx.x * TOK;

  // ---- stage means: thread stages half-row (cl = tid&255, half = tid>>8) ----
  {
    const int cl = tid & 255, hf = tid >> 8;
    const float4* src = (const float4*)(means + ((size_t)h * NK + cl) * ND + hf * 32);
    float mp = 0.f;
#pragma unroll
    for (int i = 0; i < 8; ++i) {
      float4 v = src[i];
      sm4[cl * MROW + hf * 8 + i] = v;
      mp += v.x * v.x + v.y * v.y + v.z * v.z + v.w * v.w;
    }
    smsq2[hf * NK + cl] = mp;
    if (tid < NK) scnt[tid] = 0;
  }
  __syncthreads();

  // ---- distance GEMM: acc[j][i] = dot(x[token r*4+j], means[i*32+c]) ----
  float acc[4][8];
#pragma unroll
  for (int j = 0; j < 4; ++j)
#pragma unroll
    for (int i = 0; i < 8; ++i) acc[j][i] = 0.f;

  const float* xb = x + ((size_t)(g0 + r * 4) * NH + h) * ND;   // token stride 1024 f

#pragma unroll 2
  for (int dc = 0; dc < 16; ++dc) {
    float4 xv[4];
#pragma unroll
    for (int j = 0; j < 4; ++j)
      xv[j] = *(const float4*)(xb + j * (NH * ND) + dc * 4);
#pragma unroll
    for (int i = 0; i < 8; ++i) {
      float4 mv = sm4[(i * 32 + c) * MROW + dc];
#pragma unroll
      for (int j = 0; j < 4; ++j) {
        float a = acc[j][i];
        a = fmaf(xv[j].x, mv.x, a);
        a = fmaf(xv[j].y, mv.y, a);
        a = fmaf(xv[j].z, mv.z, a);
        a = fmaf(xv[j].w, mv.w, a);
        acc[j][i] = a;
      }
    }
  }

  // ---- argmin (x_sq dropped; dist = msq - 2*dot), tie-break = smallest cluster id ----
  int bk[4];
  {
    float bv[4]; int bi_[4];
#pragma unroll
    for (int j = 0; j < 4; ++j) { bv[j] = 3.4e38f; bi_[j] = 0; }
#pragma unroll
    for (int i = 0; i < 8; ++i) {
      const int cl = i * 32 + c;
      const float mq = smsq2[cl] + smsq2[NK + cl];
#pragma unroll
      for (int j = 0; j < 4; ++j) {
        float d = mq - 2.0f * acc[j][i];
        if (d < bv[j]) { bv[j] = d; bi_[j] = cl; }
      }
    }
#pragma unroll
    for (int j = 0; j < 4; ++j) {
      float v = bv[j]; int id = bi_[j];
#pragma unroll
      for (int m = 1; m < 32; m <<= 1) {
        float ov = __shfl_xor(v, m);
        int   oi = __shfl_xor(id, m);
        if (ov < v || (ov == v && oi < id)) { v = ov; id = oi; }
      }
      bk[j] = id;
    }
    if (c == 0) {
#pragma unroll
      for (int j = 0; j < 4; ++j) {
        cids[(size_t)(g0 + r * 4 + j) * NH + h] = (uint8_t)bk[j];
        atomicAdd(&scnt[bk[j]], 1);
      }
    }
  }

  __syncthreads();                               // all means/LDS reads done
  for (int idx = tid; idx < ND * ACC_STRIDE; idx += 512) accum[idx] = 0.f;
  __syncthreads();

  // ---- EMA accumulate: col c covers d = 2c, 2c+1 for its row's 4 tokens ----
#pragma unroll
  for (int j = 0; j < 4; ++j) {
    const float* xt = x + ((size_t)(g0 + r * 4 + j) * NH + h) * ND + c * 2;
    float2 v = *(const float2*)xt;
    atomicAdd(&accum[(c * 2 + 0) * ACC_STRIDE + bk[j]], v.x);
    atomicAdd(&accum[(c * 2 + 1) * ACC_STRIDE + bk[j]], v.y);
  }

  // ---- normed_x -> out[0:56): lane = (token tl, chunk q); waves write contiguous rows ----
  {
    const int tl = tid >> 4, q = tid & 15;
#pragma unroll
    for (int rep = 0; rep < 2; ++rep) {
      const int t = tl + rep * 32;
      float4 v = *(const float4*)(x + ((size_t)(g0 + t) * NH + h) * ND + q * 4);
      float s  = v.x + v.y + v.z + v.w;
      float sq = v.x * v.x + v.y * v.y + v.z * v.z + v.w * v.w;
#pragma unroll
      for (int m = 1; m < 16; m <<= 1) { s += __shfl_xor(s, m); sq += __shfl_xor(sq, m); }
      float mu  = s * (1.f / 64.f);
      float var = sq * (1.f / 64.f) - mu * mu;
      float rs  = rsqrtf(var + 1e-5f);
      if (q < 14) {
        float4 sc = *(const float4*)(lnxs + h * ND + q * 4);
        float4 bi = *(const float4*)(lnxb + h * ND + q * 4);
        float4 o;
        o.x = (v.x - mu) * rs * sc.x + bi.x;
        o.y = (v.y - mu) * rs * sc.y + bi.y;
        o.z = (v.z - mu) * rs * sc.z + bi.z;
        o.w = (v.w - mu) * rs * sc.w + bi.w;
        *(float4*)(out + ((size_t)(g0 + t) * NH + h) * ND + q * 4) = o;
      }
    }
  }
  __syncthreads();

  // ---- flush: cluster cl = tid&255, d-half = tid>>8; skip empty clusters ----
  {
    const int cl = tid & 255, dh = tid >> 8;
    const int cnt = scnt[cl];
    if (cnt > 0) {
      if (dh == 0) atomicAdd(&gcnt[h * NK + cl], cnt);
#pragma unroll 4
      for (int d = dh * 32; d < dh * 32 + 32; ++d)
        atomicAdd(&gsum[((size_t)h * ND + d) * NK + cl], accum[d * ACC_STRIDE + cl]);
    }
  }
}

// ---------------- K2: bigram hash + embedding gather + LN_y -> out[56:64) ----------------
__global__ __launch_bounds__(256) void k_ngram(
    const uint8_t* __restrict__ cids, const float* __restrict__ embed,
    const float* __restrict__ lys, const float* __restrict__ lyb,
    float* __restrict__ out, Primes pr)
{
  const int i = blockIdx.x * 256 + threadIdx.x;  // 0 .. NBL*NH-1
  const int h = i & 15;
  const int g = i >> 4;
  const int l = g & 4095;                        // L = 4096

  int cid  = (int)cids[i];
  int prev = (l == 0) ? 0 : (int)cids[i - NH];
  int ng   = cid + (prev << 8);
  int hp1  = h + 1;
  int v    = ng * hp1 + hp1;
  const int p = pr.p[h];
  while (v >= p) v -= p;
  if (v >= NV) v -= NV;

  const float4* e4 = (const float4*)(embed + ((size_t)(v + NV * h)) * NE);
  float4 y0 = e4[0], y1 = e4[1];

  float s = ((y0.x + y0.y) + (y0.z + y0.w)) + ((y1.x + y1.y) + (y1.z + y1.w));
  float mu = s * 0.125f;
  float q = y0.x * y0.x + y0.y * y0.y + y0.z * y0.z + y0.w * y0.w
          + y1.x * y1.x + y1.y * y1.y + y1.z * y1.z + y1.w * y1.w;
  float var = q * 0.125f - mu * mu;
  float rs  = rsqrtf(var + 1e-5f);

  const float* sc = lys + h * NE;
  const float* bi = lyb + h * NE;
  float4 o0, o1;
  o0.x = (y0.x - mu) * rs * sc[0] + bi[0];
  o0.y = (y0.y - mu) * rs * sc[1] + bi[1];
  o0.z = (y0.z - mu) * rs * sc[2] + bi[2];
  o0.w = (y0.w - mu) * rs * sc[3] + bi[3];
  o1.x = (y1.x - mu) * rs * sc[4] + bi[4];
  o1.y = (y1.y - mu) * rs * sc[5] + bi[5];
  o1.z = (y1.z - mu) * rs * sc[6] + bi[6];
  o1.w = (y1.w - mu) * rs * sc[7] + bi[7];

  float4* orow = (float4*)(out + ((size_t)g * NH + h) * ND + 56);
  orow[0] = o0;
  orow[1] = o1;
}

// ---------------- K3: finalize new_means ----------------
__global__ __launch_bounds__(256) void k_means(
    const float* __restrict__ means, const float* __restrict__ gsum,
    const int* __restrict__ gcnt, float* __restrict__ newm)
{
  const int i = blockIdx.x * 256 + threadIdx.x;  // flat [h][k][d]
  const int d = i & 63;
  const int k = (i >> 6) & 255;
  const int h = i >> 14;
  float cnt = (float)gcnt[h * NK + k];
  float sx  = gsum[((size_t)h * ND + d) * NK + k];
  float mx  = sx / (1e-6f + cnt);
  newm[i] = 0.001f * mx + 0.999f * means[i];
}

extern "C" void kernel_launch(void* const* d_in, const int* in_sizes, int n_in,
                              void* d_out, int out_size, void* d_ws, size_t ws_size,
                              hipStream_t stream)
{
  const float* x     = (const float*)d_in[0];
  const float* means = (const float*)d_in[1];
  const float* embed = (const float*)d_in[2];
  const float* lnxs  = (const float*)d_in[3];
  const float* lnxb  = (const float*)d_in[4];
  const float* lys   = (const float*)d_in[5];
  const float* lyb   = (const float*)d_in[6];

  float* out  = (float*)d_out;
  float* newm = out + (size_t)NBL * NH * ND;

  float*   gsum = (float*)d_ws;
  int*     gcnt = (int*)((char*)d_ws + (size_t)NH * NK * ND * 4);
  uint8_t* cids = (uint8_t*)((char*)d_ws + (size_t)NH * NK * ND * 4 + (size_t)NH * NK * 4);

  hipMemsetAsync(d_ws, 0, (size_t)NH * NK * ND * 4 + (size_t)NH * NK * 4, stream);

  Primes pr;
  {
    int n = NV, c = 0;
    while (c < NH) {
      ++n;
      bool isp = true;
      for (int q = 2; (long long)q * q <= n; ++q)
        if (n % q == 0) { isp = false; break; }
      if (isp) pr.p[c++] = n;
    }
  }

  dim3 g1(NBL / TOK, NH);
  k_pq<<<g1, 512, 0, stream>>>(x, means, lnxs, lnxb, out, cids, gsum, gcnt);
  k_ngram<<<(NBL * NH) / 256, 256, 0, stream>>>(cids, embed, lys, lyb, out, pr);
  k_means<<<(NH * NK * ND) / 256, 256, 0, stream>>>(means, gsum, gcnt, newm);
}